// Round 7
// baseline (905.861 us; speedup 1.0000x reference)
//
#include <hip/hip_runtime.h>

#define BATCH 16
#define NQ 2048
#define NK 2048
#define KD 256

typedef short s16x8 __attribute__((ext_vector_type(8)));
typedef __bf16 bf16x8 __attribute__((ext_vector_type(8)));
typedef float f32x16 __attribute__((ext_vector_type(16)));
typedef float f32x4 __attribute__((ext_vector_type(4)));

static __device__ __forceinline__ unsigned short f2bf(float f) {
  unsigned u = __builtin_bit_cast(unsigned, f);
  u += 0x7FFFu + ((u >> 16) & 1u);   // round-to-nearest-even
  return (unsigned short)(u >> 16);
}

static __device__ __forceinline__ f32x16 mfma_bf16(s16x8 a, s16x8 b, f32x16 c) {
  return __builtin_amdgcn_mfma_f32_32x32x16_bf16(
      __builtin_bit_cast(bf16x8, a), __builtin_bit_cast(bf16x8, b), c, 0, 0, 0);
}

// WT[n][k] = W[k][n] * scale, cast to bf16.  Grid: (256, 2) x 256 thr.
// y==0: Wk (scale 1), y==1: Wq (scale 1/16, folds 1/sqrt(256)).
__global__ void prep_wt(const float* __restrict__ Wk, unsigned short* __restrict__ WkT,
                        const float* __restrict__ Wq, unsigned short* __restrict__ WqT) {
  const float* W = blockIdx.y ? Wq : Wk;
  unsigned short* WT = blockIdx.y ? WqT : WkT;
  float scale = blockIdx.y ? 0.0625f : 1.0f;
  int idx = blockIdx.x * 256 + threadIdx.x;
  int n = idx >> 8, k = idx & 255;
  WT[n * 256 + k] = f2bf(W[k * 256 + n] * scale);
}

// Projection, output written in MFMA-FRAGMENT order:
//   Yf[((g*16 + kk)*64 + khe*32 + n31)*8 + j]  holds  Y[row=g*32+n31][e=kk*16+khe*8+j]
// where g = global 32-row tile (b*64 + n>>5).  A fragment load in attn is then
// 64 lanes x consecutive 16 B = 1 KB coalesced.
__global__ __launch_bounds__(256, 2) void proj_kernel(
    const float* __restrict__ Xk, const unsigned short* __restrict__ WkT,
    unsigned short* __restrict__ Yk,
    const float* __restrict__ Xq, const unsigned short* __restrict__ WqT,
    unsigned short* __restrict__ Yq) {
  const float* X;
  const unsigned short* WT;
  unsigned short* Y;
  if (blockIdx.y == 0) { X = Xk; WT = WkT; Y = Yk; }
  else                 { X = Xq; WT = WqT; Y = Yq; }

  int tid = threadIdx.x;
  int wave = tid >> 6, lane = tid & 63;
  int l31 = lane & 31, kh = lane >> 5;
  int r0 = blockIdx.x * 128 + wave * 32;

  const float* xp = X + (size_t)(r0 + l31) * 256 + kh * 8;

  f32x16 acc[8];
#pragma unroll
  for (int ct = 0; ct < 8; ++ct)
#pragma unroll
    for (int i = 0; i < 16; ++i) acc[ct][i] = 0.0f;

#pragma unroll
  for (int kk = 0; kk < 16; ++kk) {
    f32x4 a0 = *(const f32x4*)(xp + kk * 16);
    f32x4 a1 = *(const f32x4*)(xp + kk * 16 + 4);
    s16x8 af;
#pragma unroll
    for (int j = 0; j < 4; ++j) {
      af[j]     = (short)f2bf(a0[j]);
      af[4 + j] = (short)f2bf(a1[j]);
    }
#pragma unroll
    for (int ct = 0; ct < 8; ++ct) {
      s16x8 bw = *(const s16x8*)(WT + (size_t)(ct * 32 + l31) * 256 + kk * 16 + kh * 8);
      acc[ct] = mfma_bf16(af, bw, acc[ct]);
    }
  }

  size_t gbase = (size_t)(r0 >> 5) * 16;   // global 32-row tile index * 16
#pragma unroll
  for (int ct = 0; ct < 8; ++ct) {
    int ecol = ct * 32 + l31;
    size_t cbase = (gbase + (ecol >> 4)) * 64 * 8 + ((ecol >> 3) & 1) * 32 * 8 + (ecol & 7);
#pragma unroll
    for (int r = 0; r < 16; ++r) {
      int rrow = (r & 3) + 8 * (r >> 2) + 4 * kh;   // n31 within the tile
      Y[cbase + rrow * 8] = f2bf(acc[ct][r]);
    }
  }
}

// Fused adjacency-pack + scores + tanh-clip + mask + softmax.
// Grid: (64, 16) = 1024 blocks, 512 threads (8 waves).
// Register-lean two-pass form:
//   - Q fragments live in LDS (16 KB), read via ds_read_b128 per MFMA (-64 VGPR)
//   - no P stash: pass 1 accumulates row sums, pass 2 recomputes scores and
//     writes normalized output (-64 VGPR; MFMA was 6.5% util, doubling is free)
// -> true per-wave regs ~<100, so __launch_bounds__(512,4) is met WITHOUT
//    spilling and >=2 blocks/CU become resident (was 1 block/CU, occ 21%).
// XCD-aware remap: xcd = lin&7 owns batches {2*xcd, 2*xcd+1} (2 MB K / L2).
__global__ __launch_bounds__(512, 4) void attn_kernel(
    const unsigned short* __restrict__ Kf, const unsigned short* __restrict__ Qf,
    const int* __restrict__ adj, float* __restrict__ out) {
  int lin = blockIdx.y * 64 + blockIdx.x;
  int b  = (lin & 7) * 2 + ((lin >> 3) & 1);
  int qt = lin >> 4;
  int q0 = qt * 32;
  int tid = threadIdx.x;
  int wave = tid >> 6, lane = tid & 63;
  int l31 = lane & 31, kh = lane >> 5;
  int colbase = wave * 256;

  __shared__ unsigned short qlds[16 * 512];   // 16 KB: Q tile, fragment order
  __shared__ unsigned lmask[8 * 256];         // 8 KB: [wave][row 0..31][word 0..7]
  __shared__ float wsum[8][32];
  __shared__ float rrecip[32];

  // ---- stage Q tile into LDS (coalesced, 2 x 8 KB rounds) ----
  const unsigned short* qp = Qf + ((size_t)(b * 64 + qt) * 16) * 512;
  ((s16x8*)qlds)[tid]       = ((const s16x8*)qp)[tid];
  ((s16x8*)qlds)[tid + 512] = ((const s16x8*)qp)[tid + 512];

  // ---- wave-local pack: cols [wave*256, wave*256+256) for rows 0..31 ----
  const int* abase = adj + ((size_t)b * NQ + q0) * (size_t)NK + colbase + lane;
  unsigned* lm = lmask + wave * 256;
#pragma unroll
  for (int rg = 0; rg < 4; ++rg) {
    int av[8][4];
#pragma unroll
    for (int r8 = 0; r8 < 8; ++r8) {
      const int* ap = abase + (size_t)(rg * 8 + r8) * NK;
#pragma unroll
      for (int cc = 0; cc < 4; ++cc) av[r8][cc] = ap[cc * 64];
    }
#pragma unroll
    for (int r8 = 0; r8 < 8; ++r8) {
      unsigned long long b0 = __ballot(av[r8][0] != 0);   // cols 0..63 of range
      unsigned long long b1 = __ballot(av[r8][1] != 0);   // cols 64..127
      unsigned long long b2 = __ballot(av[r8][2] != 0);   // cols 128..191
      unsigned long long b3 = __ballot(av[r8][3] != 0);   // cols 192..255
      if (lane < 8) {   // lane j stores word j (cols j*32 .. j*32+31)
        unsigned long long bb = (lane & 4) ? ((lane & 2) ? b3 : b2)
                                           : ((lane & 2) ? b1 : b0);
        unsigned word = (lane & 1) ? (unsigned)(bb >> 32) : (unsigned)bb;
        lm[(rg * 8 + r8) * 8 + lane] = word;
      }
    }
  }

  __syncthreads();  // qlds staged by all waves; lmask wave-local anyway

  const unsigned short* kfb = Kf + ((size_t)b * 64 * 16) * 512;
  unsigned bit = 1u << l31;

  // ---- PASS 1: scores -> row sums only ----
  float rsum[16];
#pragma unroll
  for (int r = 0; r < 16; ++r) rsum[r] = 0.0f;

#pragma unroll
  for (int ct = 0; ct < 8; ++ct) {
    f32x16 acc;
#pragma unroll
    for (int i = 0; i < 16; ++i) acc[i] = 0.0f;
    const unsigned short* kpt = kfb + ((size_t)(wave * 8 + ct) * 16) * 512;
#pragma unroll
    for (int kk = 0; kk < 16; ++kk) {
      s16x8 a  = *(const s16x8*)(qlds + (kk * 64 + lane) * 8);
      s16x8 bk = *(const s16x8*)(kpt + (kk * 64 + lane) * 8);
      acc = mfma_bf16(a, bk, acc);
    }
#pragma unroll
    for (int r = 0; r < 16; ++r) {
      int rrow = (r & 3) + 8 * (r >> 2) + 4 * kh;
      unsigned mw = lm[rrow * 8 + ct];
      float s  = acc[r];
      float u  = __builtin_amdgcn_exp2f(s * 2.885390081777927f);   // e^(2s)
      float th = 1.0f - 2.0f * __builtin_amdgcn_rcpf(u + 1.0f);    // tanh(s)
      float e  = __builtin_amdgcn_exp2f((10.0f * th - 10.0f) * 1.44269504088896f);
      rsum[r] += (mw & bit) ? e : 0.0f;
    }
  }

  // reduce row sums across the 32 cols of this half-wave (rows differ by kh)
#pragma unroll
  for (int r = 0; r < 16; ++r) {
    float v = rsum[r];
    v += __shfl_xor(v, 1);
    v += __shfl_xor(v, 2);
    v += __shfl_xor(v, 4);
    v += __shfl_xor(v, 8);
    v += __shfl_xor(v, 16);
    rsum[r] = v;
  }
  if (l31 == 0) {
#pragma unroll
    for (int r = 0; r < 16; ++r)
      wsum[wave][(r & 3) + 8 * (r >> 2) + 4 * kh] = rsum[r];
  }
  __syncthreads();
  if (tid < 32) {
    float s = 0.0f;
#pragma unroll
    for (int w = 0; w < 8; ++w) s += wsum[w][tid];
    rrecip[tid] = 1.0f / s;
  }
  __syncthreads();

  float rc[16];
#pragma unroll
  for (int r = 0; r < 16; ++r) rc[r] = rrecip[(r & 3) + 8 * (r >> 2) + 4 * kh];

  // ---- PASS 2: recompute scores, normalize, store ----
  float* op = out + ((size_t)b * NQ + q0) * (size_t)NK + colbase + l31;
#pragma unroll
  for (int ct = 0; ct < 8; ++ct) {
    f32x16 acc;
#pragma unroll
    for (int i = 0; i < 16; ++i) acc[i] = 0.0f;
    const unsigned short* kpt = kfb + ((size_t)(wave * 8 + ct) * 16) * 512;
#pragma unroll
    for (int kk = 0; kk < 16; ++kk) {
      s16x8 a  = *(const s16x8*)(qlds + (kk * 64 + lane) * 8);
      s16x8 bk = *(const s16x8*)(kpt + (kk * 64 + lane) * 8);
      acc = mfma_bf16(a, bk, acc);
    }
#pragma unroll
    for (int r = 0; r < 16; ++r) {
      int rrow = (r & 3) + 8 * (r >> 2) + 4 * kh;
      unsigned mw = lm[rrow * 8 + ct];
      float s  = acc[r];
      float u  = __builtin_amdgcn_exp2f(s * 2.885390081777927f);
      float th = 1.0f - 2.0f * __builtin_amdgcn_rcpf(u + 1.0f);
      float e  = __builtin_amdgcn_exp2f((10.0f * th - 10.0f) * 1.44269504088896f);
      float p  = (mw & bit) ? e : 0.0f;
      op[(size_t)rrow * NK + ct * 32] = p * rc[r];
    }
  }
}

extern "C" void kernel_launch(void* const* d_in, const int* in_sizes, int n_in,
                              void* d_out, int out_size, void* d_ws, size_t ws_size,
                              hipStream_t stream) {
  const float* k_in = (const float*)d_in[0];
  const float* q_in = (const float*)d_in[1];
  const int* adj    = (const int*)d_in[2];
  const float* Wk   = (const float*)d_in[3];
  const float* Wq   = (const float*)d_in[4];
  float* out = (float*)d_out;

  char* ws = (char*)d_ws;
  unsigned short* WkT = (unsigned short*)(ws);                           // 128 KB
  unsigned short* WqT = (unsigned short*)(ws + (1u << 17));              // 128 KB
  unsigned short* Kf  = (unsigned short*)(ws + (1u << 18));              // 16 MB
  unsigned short* Qf  = (unsigned short*)(ws + (1u << 18) + (1u << 24)); // 16 MB

  prep_wt<<<dim3(256, 2), 256, 0, stream>>>(Wk, WkT, Wq, WqT);

  proj_kernel<<<dim3(256, 2), 256, 0, stream>>>(k_in, WkT, Kf, q_in, WqT, Qf);

  attn_kernel<<<dim3(64, 16), 512, 0, stream>>>(Kf, Qf, adj, out);
}

// Round 8
// 589.840 us; speedup vs baseline: 1.5358x; 1.5358x over previous
//
#include <hip/hip_runtime.h>

#define BATCH 16
#define NQ 2048
#define NK 2048
#define KD 256

typedef short s16x8 __attribute__((ext_vector_type(8)));
typedef __bf16 bf16x8 __attribute__((ext_vector_type(8)));
typedef float f32x16 __attribute__((ext_vector_type(16)));
typedef float f32x4 __attribute__((ext_vector_type(4)));

static __device__ __forceinline__ unsigned short f2bf(float f) {
  unsigned u = __builtin_bit_cast(unsigned, f);
  u += 0x7FFFu + ((u >> 16) & 1u);   // round-to-nearest-even
  return (unsigned short)(u >> 16);
}

static __device__ __forceinline__ f32x16 mfma_bf16(s16x8 a, s16x8 b, f32x16 c) {
  return __builtin_amdgcn_mfma_f32_32x32x16_bf16(
      __builtin_bit_cast(bf16x8, a), __builtin_bit_cast(bf16x8, b), c, 0, 0, 0);
}

// WT[n][k] = W[k][n] * scale, cast to bf16.  Grid: (256, 2) x 256 thr.
// y==0: Wk (scale 1), y==1: Wq (scale 1/16, folds 1/sqrt(256)).
__global__ void prep_wt(const float* __restrict__ Wk, unsigned short* __restrict__ WkT,
                        const float* __restrict__ Wq, unsigned short* __restrict__ WqT) {
  const float* W = blockIdx.y ? Wq : Wk;
  unsigned short* WT = blockIdx.y ? WqT : WkT;
  float scale = blockIdx.y ? 0.0625f : 1.0f;
  int idx = blockIdx.x * 256 + threadIdx.x;
  int n = idx >> 8, k = idx & 255;
  WT[n * 256 + k] = f2bf(W[k * 256 + n] * scale);
}

// Projection, output written in MFMA-FRAGMENT order:
//   Yf[((g*16 + kk)*64 + khe*32 + n31)*8 + j]  holds  Y[row=g*32+n31][e=kk*16+khe*8+j]
// where g = global 32-row tile (b*64 + n>>5).  A fragment load in attn is then
// 64 lanes x consecutive 16 B = 1 KB coalesced.
__global__ __launch_bounds__(256, 2) void proj_kernel(
    const float* __restrict__ Xk, const unsigned short* __restrict__ WkT,
    unsigned short* __restrict__ Yk,
    const float* __restrict__ Xq, const unsigned short* __restrict__ WqT,
    unsigned short* __restrict__ Yq) {
  const float* X;
  const unsigned short* WT;
  unsigned short* Y;
  if (blockIdx.y == 0) { X = Xk; WT = WkT; Y = Yk; }
  else                 { X = Xq; WT = WqT; Y = Yq; }

  int tid = threadIdx.x;
  int wave = tid >> 6, lane = tid & 63;
  int l31 = lane & 31, kh = lane >> 5;
  int r0 = blockIdx.x * 128 + wave * 32;

  const float* xp = X + (size_t)(r0 + l31) * 256 + kh * 8;

  f32x16 acc[8];
#pragma unroll
  for (int ct = 0; ct < 8; ++ct)
#pragma unroll
    for (int i = 0; i < 16; ++i) acc[ct][i] = 0.0f;

#pragma unroll
  for (int kk = 0; kk < 16; ++kk) {
    f32x4 a0 = *(const f32x4*)(xp + kk * 16);
    f32x4 a1 = *(const f32x4*)(xp + kk * 16 + 4);
    s16x8 af;
#pragma unroll
    for (int j = 0; j < 4; ++j) {
      af[j]     = (short)f2bf(a0[j]);
      af[4 + j] = (short)f2bf(a1[j]);
    }
#pragma unroll
    for (int ct = 0; ct < 8; ++ct) {
      s16x8 bw = *(const s16x8*)(WT + (size_t)(ct * 32 + l31) * 256 + kk * 16 + kh * 8);
      acc[ct] = mfma_bf16(af, bw, acc[ct]);
    }
  }

  size_t gbase = (size_t)(r0 >> 5) * 16;   // global 32-row tile index * 16
#pragma unroll
  for (int ct = 0; ct < 8; ++ct) {
    int ecol = ct * 32 + l31;
    size_t cbase = (gbase + (ecol >> 4)) * 64 * 8 + ((ecol >> 3) & 1) * 32 * 8 + (ecol & 7);
#pragma unroll
    for (int r = 0; r < 16; ++r) {
      int rrow = (r & 3) + 8 * (r >> 2) + 4 * kh;   // n31 within the tile
      Y[cbase + rrow * 8] = f2bf(acc[ct][r]);
    }
  }
}

// Fused adjacency-pack + scores + tanh-clip + mask + softmax.
// Grid: (64, 16) = 1024 blocks, 512 threads (8 waves).
// Register-lean two-pass form:
//   - Q fragments live in LDS (16 KB), read via ds_read_b128 per MFMA (-64 VGPR)
//   - no P stash: pass 1 accumulates row sums, pass 2 recomputes scores and
//     writes normalized output (-64 VGPR; MFMA util was 6.5%, doubling is free)
// __launch_bounds__ arg2 on this toolchain acts as CUDA-style min-BLOCKS/CU:
//   (512,4) -> 32 waves/CU budget -> 64 VGPR -> catastrophic spills (R5, R7).
//   (512,2) -> 16 waves/CU budget -> 128 VGPR; true need ~90 -> no spills,
//   and 2 blocks/CU become resident via the register file.
// XCD-aware remap: xcd = lin&7 owns batches {2*xcd, 2*xcd+1} (2 MB K / L2).
__global__ __launch_bounds__(512, 2) void attn_kernel(
    const unsigned short* __restrict__ Kf, const unsigned short* __restrict__ Qf,
    const int* __restrict__ adj, float* __restrict__ out) {
  int lin = blockIdx.y * 64 + blockIdx.x;
  int b  = (lin & 7) * 2 + ((lin >> 3) & 1);
  int qt = lin >> 4;
  int q0 = qt * 32;
  int tid = threadIdx.x;
  int wave = tid >> 6, lane = tid & 63;
  int l31 = lane & 31, kh = lane >> 5;
  int colbase = wave * 256;

  __shared__ unsigned short qlds[16 * 512];   // 16 KB: Q tile, fragment order
  __shared__ unsigned lmask[8 * 256];         // 8 KB: [wave][row 0..31][word 0..7]
  __shared__ float wsum[8][32];
  __shared__ float rrecip[32];

  // ---- stage Q tile into LDS (coalesced, 2 x 8 KB rounds) ----
  const unsigned short* qp = Qf + ((size_t)(b * 64 + qt) * 16) * 512;
  ((s16x8*)qlds)[tid]       = ((const s16x8*)qp)[tid];
  ((s16x8*)qlds)[tid + 512] = ((const s16x8*)qp)[tid + 512];

  // ---- wave-local pack: cols [wave*256, wave*256+256) for rows 0..31 ----
  const int* abase = adj + ((size_t)b * NQ + q0) * (size_t)NK + colbase + lane;
  unsigned* lm = lmask + wave * 256;
#pragma unroll
  for (int rg = 0; rg < 4; ++rg) {
    int av[8][4];
#pragma unroll
    for (int r8 = 0; r8 < 8; ++r8) {
      const int* ap = abase + (size_t)(rg * 8 + r8) * NK;
#pragma unroll
      for (int cc = 0; cc < 4; ++cc) av[r8][cc] = ap[cc * 64];
    }
#pragma unroll
    for (int r8 = 0; r8 < 8; ++r8) {
      unsigned long long b0 = __ballot(av[r8][0] != 0);   // cols 0..63 of range
      unsigned long long b1 = __ballot(av[r8][1] != 0);   // cols 64..127
      unsigned long long b2 = __ballot(av[r8][2] != 0);   // cols 128..191
      unsigned long long b3 = __ballot(av[r8][3] != 0);   // cols 192..255
      if (lane < 8) {   // lane j stores word j (cols j*32 .. j*32+31)
        unsigned long long bb = (lane & 4) ? ((lane & 2) ? b3 : b2)
                                           : ((lane & 2) ? b1 : b0);
        unsigned word = (lane & 1) ? (unsigned)(bb >> 32) : (unsigned)bb;
        lm[(rg * 8 + r8) * 8 + lane] = word;
      }
    }
  }

  __syncthreads();  // qlds staged by all waves

  const unsigned short* kfb = Kf + ((size_t)b * 64 * 16) * 512;
  unsigned bit = 1u << l31;

  // ---- PASS 1: scores -> row sums only ----
  float rsum[16];
#pragma unroll
  for (int r = 0; r < 16; ++r) rsum[r] = 0.0f;

#pragma unroll
  for (int ct = 0; ct < 8; ++ct) {
    f32x16 acc;
#pragma unroll
    for (int i = 0; i < 16; ++i) acc[i] = 0.0f;
    const unsigned short* kpt = kfb + ((size_t)(wave * 8 + ct) * 16) * 512;
#pragma unroll
    for (int kk = 0; kk < 16; ++kk) {
      s16x8 a  = *(const s16x8*)(qlds + (kk * 64 + lane) * 8);
      s16x8 bk = *(const s16x8*)(kpt + (kk * 64 + lane) * 8);
      acc = mfma_bf16(a, bk, acc);
    }
#pragma unroll
    for (int r = 0; r < 16; ++r) {
      int rrow = (r & 3) + 8 * (r >> 2) + 4 * kh;
      unsigned mw = lm[rrow * 8 + ct];
      float s  = acc[r];
      float u  = __builtin_amdgcn_exp2f(s * 2.885390081777927f);   // e^(2s)
      float th = 1.0f - 2.0f * __builtin_amdgcn_rcpf(u + 1.0f);    // tanh(s)
      float e  = __builtin_amdgcn_exp2f((10.0f * th - 10.0f) * 1.44269504088896f);
      rsum[r] += (mw & bit) ? e : 0.0f;
    }
  }

  // reduce row sums across the 32 cols of this half-wave (rows differ by kh)
#pragma unroll
  for (int r = 0; r < 16; ++r) {
    float v = rsum[r];
    v += __shfl_xor(v, 1);
    v += __shfl_xor(v, 2);
    v += __shfl_xor(v, 4);
    v += __shfl_xor(v, 8);
    v += __shfl_xor(v, 16);
    rsum[r] = v;
  }
  if (l31 == 0) {
#pragma unroll
    for (int r = 0; r < 16; ++r)
      wsum[wave][(r & 3) + 8 * (r >> 2) + 4 * kh] = rsum[r];
  }
  __syncthreads();
  if (tid < 32) {
    float s = 0.0f;
#pragma unroll
    for (int w = 0; w < 8; ++w) s += wsum[w][tid];
    rrecip[tid] = 1.0f / s;
  }
  __syncthreads();

  float rc[16];
#pragma unroll
  for (int r = 0; r < 16; ++r) rc[r] = rrecip[(r & 3) + 8 * (r >> 2) + 4 * kh];

  // ---- PASS 2: recompute scores, normalize, store ----
  float* op = out + ((size_t)b * NQ + q0) * (size_t)NK + colbase + l31;
#pragma unroll
  for (int ct = 0; ct < 8; ++ct) {
    f32x16 acc;
#pragma unroll
    for (int i = 0; i < 16; ++i) acc[i] = 0.0f;
    const unsigned short* kpt = kfb + ((size_t)(wave * 8 + ct) * 16) * 512;
#pragma unroll
    for (int kk = 0; kk < 16; ++kk) {
      s16x8 a  = *(const s16x8*)(qlds + (kk * 64 + lane) * 8);
      s16x8 bk = *(const s16x8*)(kpt + (kk * 64 + lane) * 8);
      acc = mfma_bf16(a, bk, acc);
    }
#pragma unroll
    for (int r = 0; r < 16; ++r) {
      int rrow = (r & 3) + 8 * (r >> 2) + 4 * kh;
      unsigned mw = lm[rrow * 8 + ct];
      float s  = acc[r];
      float u  = __builtin_amdgcn_exp2f(s * 2.885390081777927f);
      float th = 1.0f - 2.0f * __builtin_amdgcn_rcpf(u + 1.0f);
      float e  = __builtin_amdgcn_exp2f((10.0f * th - 10.0f) * 1.44269504088896f);
      float p  = (mw & bit) ? e : 0.0f;
      op[(size_t)rrow * NK + ct * 32] = p * rc[r];
    }
  }
}

extern "C" void kernel_launch(void* const* d_in, const int* in_sizes, int n_in,
                              void* d_out, int out_size, void* d_ws, size_t ws_size,
                              hipStream_t stream) {
  const float* k_in = (const float*)d_in[0];
  const float* q_in = (const float*)d_in[1];
  const int* adj    = (const int*)d_in[2];
  const float* Wk   = (const float*)d_in[3];
  const float* Wq   = (const float*)d_in[4];
  float* out = (float*)d_out;

  char* ws = (char*)d_ws;
  unsigned short* WkT = (unsigned short*)(ws);                           // 128 KB
  unsigned short* WqT = (unsigned short*)(ws + (1u << 17));              // 128 KB
  unsigned short* Kf  = (unsigned short*)(ws + (1u << 18));              // 16 MB
  unsigned short* Qf  = (unsigned short*)(ws + (1u << 18) + (1u << 24)); // 16 MB

  prep_wt<<<dim3(256, 2), 256, 0, stream>>>(Wk, WkT, Wq, WqT);

  proj_kernel<<<dim3(256, 2), 256, 0, stream>>>(k_in, WkT, Kf, q_in, WqT, Qf);

  attn_kernel<<<dim3(64, 16), 512, 0, stream>>>(Kf, Qf, adj, out);
}

// Round 9
// 497.684 us; speedup vs baseline: 1.8202x; 1.1852x over previous
//
#include <hip/hip_runtime.h>

#define BATCH 16
#define NQ 2048
#define NK 2048
#define KD 256

typedef short s16x8 __attribute__((ext_vector_type(8)));
typedef __bf16 bf16x8 __attribute__((ext_vector_type(8)));
typedef float f32x16 __attribute__((ext_vector_type(16)));
typedef float f32x4 __attribute__((ext_vector_type(4)));

static __device__ __forceinline__ unsigned short f2bf(float f) {
  unsigned u = __builtin_bit_cast(unsigned, f);
  u += 0x7FFFu + ((u >> 16) & 1u);   // round-to-nearest-even
  return (unsigned short)(u >> 16);
}

static __device__ __forceinline__ f32x16 mfma_bf16(s16x8 a, s16x8 b, f32x16 c) {
  return __builtin_amdgcn_mfma_f32_32x32x16_bf16(
      __builtin_bit_cast(bf16x8, a), __builtin_bit_cast(bf16x8, b), c, 0, 0, 0);
}

// p = exp(10*tanh(s) - 10) = exp2(-28.8539008.../(e^(2s)+1)), e^(2s)=exp2(2.885390*s)
static __device__ __forceinline__ float score_p(float s) {
  float u = __builtin_amdgcn_exp2f(s * 2.885390081777927f);
  return __builtin_amdgcn_exp2f(-28.853900817779268f * __builtin_amdgcn_rcpf(u + 1.0f));
}

// WT[n][k] = W[k][n] * scale, cast to bf16.  Grid: (256, 2) x 256 thr.
// y==0: Wk (scale 1), y==1: Wq (scale 1/16, folds 1/sqrt(256)).
__global__ void prep_wt(const float* __restrict__ Wk, unsigned short* __restrict__ WkT,
                        const float* __restrict__ Wq, unsigned short* __restrict__ WqT) {
  const float* W = blockIdx.y ? Wq : Wk;
  unsigned short* WT = blockIdx.y ? WqT : WkT;
  float scale = blockIdx.y ? 0.0625f : 1.0f;
  int idx = blockIdx.x * 256 + threadIdx.x;
  int n = idx >> 8, k = idx & 255;
  WT[n * 256 + k] = f2bf(W[k * 256 + n] * scale);
}

// Projection, output written in MFMA-FRAGMENT order:
//   Yf[((g*16 + kk)*64 + khe*32 + n31)*8 + j]  holds  Y[row=g*32+n31][e=kk*16+khe*8+j]
// where g = global 32-row tile (b*64 + n>>5).  A fragment load in attn is then
// 64 lanes x consecutive 16 B = 1 KB coalesced.
__global__ __launch_bounds__(256, 2) void proj_kernel(
    const float* __restrict__ Xk, const unsigned short* __restrict__ WkT,
    unsigned short* __restrict__ Yk,
    const float* __restrict__ Xq, const unsigned short* __restrict__ WqT,
    unsigned short* __restrict__ Yq) {
  const float* X;
  const unsigned short* WT;
  unsigned short* Y;
  if (blockIdx.y == 0) { X = Xk; WT = WkT; Y = Yk; }
  else                 { X = Xq; WT = WqT; Y = Yq; }

  int tid = threadIdx.x;
  int wave = tid >> 6, lane = tid & 63;
  int l31 = lane & 31, kh = lane >> 5;
  int r0 = blockIdx.x * 128 + wave * 32;

  const float* xp = X + (size_t)(r0 + l31) * 256 + kh * 8;

  f32x16 acc[8];
#pragma unroll
  for (int ct = 0; ct < 8; ++ct)
#pragma unroll
    for (int i = 0; i < 16; ++i) acc[ct][i] = 0.0f;

#pragma unroll
  for (int kk = 0; kk < 16; ++kk) {
    f32x4 a0 = *(const f32x4*)(xp + kk * 16);
    f32x4 a1 = *(const f32x4*)(xp + kk * 16 + 4);
    s16x8 af;
#pragma unroll
    for (int j = 0; j < 4; ++j) {
      af[j]     = (short)f2bf(a0[j]);
      af[4 + j] = (short)f2bf(a1[j]);
    }
#pragma unroll
    for (int ct = 0; ct < 8; ++ct) {
      s16x8 bw = *(const s16x8*)(WT + (size_t)(ct * 32 + l31) * 256 + kk * 16 + kh * 8);
      acc[ct] = mfma_bf16(af, bw, acc[ct]);
    }
  }

  size_t gbase = (size_t)(r0 >> 5) * 16;   // global 32-row tile index * 16
#pragma unroll
  for (int ct = 0; ct < 8; ++ct) {
    int ecol = ct * 32 + l31;
    size_t cbase = (gbase + (ecol >> 4)) * 64 * 8 + ((ecol >> 3) & 1) * 32 * 8 + (ecol & 7);
#pragma unroll
    for (int r = 0; r < 16; ++r) {
      int rrow = (r & 3) + 8 * (r >> 2) + 4 * kh;   // n31 within the tile
      Y[cbase + rrow * 8] = f2bf(acc[ct][r]);
    }
  }
}

// Fused adjacency-pack + scores + tanh-clip + mask + softmax.
// Grid: (64, 16) = 1024 blocks, 512 threads (8 waves), two-pass (no P stash):
//   pass 1: scores -> row sums; pass 2: recompute scores, scale, store.
// Q fragments live in LDS; an OPAQUE offset (asm "+v") inside each ct
// iteration stops LICM from hoisting the 16 fragment reads (the 64-VGPR
// hoist is what spilled R8: VGPR cap 128 + hoist -> scratch 500+ MB).
// Target: ~100 VGPR + 16 AGPR <= 128 total -> 2 blocks/CU resident.
// XCD-aware remap: xcd = lin&7 owns batches {2*xcd, 2*xcd+1} (2 MB K / L2).
__global__ __launch_bounds__(512, 2) void attn_kernel(
    const unsigned short* __restrict__ Kf, const unsigned short* __restrict__ Qf,
    const int* __restrict__ adj, float* __restrict__ out) {
  int lin = blockIdx.y * 64 + blockIdx.x;
  int b  = (lin & 7) * 2 + ((lin >> 3) & 1);
  int qt = lin >> 4;
  int q0 = qt * 32;
  int tid = threadIdx.x;
  int wave = tid >> 6, lane = tid & 63;
  int l31 = lane & 31, kh = lane >> 5;
  int colbase = wave * 256;

  __shared__ unsigned short qlds[16 * 512];   // 16 KB: Q tile, fragment order
  __shared__ unsigned lmask[8 * 256];         // 8 KB: [wave][row 0..31][word 0..7]
  __shared__ float wsum[8][32];
  __shared__ float rrecip[32];

  // ---- stage Q tile into LDS (coalesced, 2 x 8 KB rounds) ----
  const unsigned short* qp = Qf + ((size_t)(b * 64 + qt) * 16) * 512;
  ((s16x8*)qlds)[tid]       = ((const s16x8*)qp)[tid];
  ((s16x8*)qlds)[tid + 512] = ((const s16x8*)qp)[tid + 512];

  // ---- wave-local pack: cols [wave*256, wave*256+256) for rows 0..31 ----
  const int* abase = adj + ((size_t)b * NQ + q0) * (size_t)NK + colbase + lane;
  unsigned* lm = lmask + wave * 256;
#pragma unroll
  for (int rg = 0; rg < 4; ++rg) {
    int av[8][4];
#pragma unroll
    for (int r8 = 0; r8 < 8; ++r8) {
      const int* ap = abase + (size_t)(rg * 8 + r8) * NK;
#pragma unroll
      for (int cc = 0; cc < 4; ++cc) av[r8][cc] = ap[cc * 64];
    }
#pragma unroll
    for (int r8 = 0; r8 < 8; ++r8) {
      unsigned long long b0 = __ballot(av[r8][0] != 0);   // cols 0..63 of range
      unsigned long long b1 = __ballot(av[r8][1] != 0);   // cols 64..127
      unsigned long long b2 = __ballot(av[r8][2] != 0);   // cols 128..191
      unsigned long long b3 = __ballot(av[r8][3] != 0);   // cols 192..255
      if (lane < 8) {   // lane j stores word j (cols j*32 .. j*32+31)
        unsigned long long bb = (lane & 4) ? ((lane & 2) ? b3 : b2)
                                           : ((lane & 2) ? b1 : b0);
        unsigned word = (lane & 1) ? (unsigned)(bb >> 32) : (unsigned)bb;
        lm[(rg * 8 + r8) * 8 + lane] = word;
      }
    }
  }

  __syncthreads();  // qlds staged by all waves

  const unsigned short* kfb = Kf + ((size_t)b * 64 * 16) * 512;
  unsigned bit = 1u << l31;

  // ---- PASS 1: scores -> row sums only ----
  float rsum[16];
#pragma unroll
  for (int r = 0; r < 16; ++r) rsum[r] = 0.0f;

#pragma unroll
  for (int ct = 0; ct < 8; ++ct) {
    unsigned qoff = 0;
    asm volatile("" : "+v"(qoff));   // opaque: defeats LICM hoist of q-frag reads
    f32x16 acc;
#pragma unroll
    for (int i = 0; i < 16; ++i) acc[i] = 0.0f;
    const unsigned short* kpt = kfb + ((size_t)(wave * 8 + ct) * 16) * 512;
#pragma unroll
    for (int kk = 0; kk < 16; ++kk) {
      s16x8 a  = *(const s16x8*)(qlds + qoff + (kk * 64 + lane) * 8);
      s16x8 bk = *(const s16x8*)(kpt + (kk * 64 + lane) * 8);
      acc = mfma_bf16(a, bk, acc);
    }
#pragma unroll
    for (int r = 0; r < 16; ++r) {
      int rrow = (r & 3) + 8 * (r >> 2) + 4 * kh;
      unsigned mw = lm[rrow * 8 + ct];
      float p = score_p(acc[r]);
      rsum[r] += (mw & bit) ? p : 0.0f;
    }
  }

  // reduce row sums across the 32 cols of this half-wave (rows differ by kh)
#pragma unroll
  for (int r = 0; r < 16; ++r) {
    float v = rsum[r];
    v += __shfl_xor(v, 1);
    v += __shfl_xor(v, 2);
    v += __shfl_xor(v, 4);
    v += __shfl_xor(v, 8);
    v += __shfl_xor(v, 16);
    rsum[r] = v;
  }
  if (l31 == 0) {
#pragma unroll
    for (int r = 0; r < 16; ++r)
      wsum[wave][(r & 3) + 8 * (r >> 2) + 4 * kh] = rsum[r];
  }
  __syncthreads();
  if (tid < 32) {
    float s = 0.0f;
#pragma unroll
    for (int w = 0; w < 8; ++w) s += wsum[w][tid];
    rrecip[tid] = 1.0f / s;
  }
  __syncthreads();

  // ---- PASS 2: recompute scores, normalize, store ----
  float* op = out + ((size_t)b * NQ + q0) * (size_t)NK + colbase + l31;
#pragma unroll
  for (int ct = 0; ct < 8; ++ct) {
    unsigned qoff = 0;
    asm volatile("" : "+v"(qoff));   // opaque: defeats LICM hoist of q-frag reads
    f32x16 acc;
#pragma unroll
    for (int i = 0; i < 16; ++i) acc[i] = 0.0f;
    const unsigned short* kpt = kfb + ((size_t)(wave * 8 + ct) * 16) * 512;
#pragma unroll
    for (int kk = 0; kk < 16; ++kk) {
      s16x8 a  = *(const s16x8*)(qlds + qoff + (kk * 64 + lane) * 8);
      s16x8 bk = *(const s16x8*)(kpt + (kk * 64 + lane) * 8);
      acc = mfma_bf16(a, bk, acc);
    }
#pragma unroll
    for (int r = 0; r < 16; ++r) {
      int rrow = (r & 3) + 8 * (r >> 2) + 4 * kh;
      unsigned mw = lm[rrow * 8 + ct];
      float p = (mw & bit) ? score_p(acc[r]) : 0.0f;
      op[(size_t)rrow * NK + ct * 32] = p * rrecip[rrow];
    }
  }
}

extern "C" void kernel_launch(void* const* d_in, const int* in_sizes, int n_in,
                              void* d_out, int out_size, void* d_ws, size_t ws_size,
                              hipStream_t stream) {
  const float* k_in = (const float*)d_in[0];
  const float* q_in = (const float*)d_in[1];
  const int* adj    = (const int*)d_in[2];
  const float* Wk   = (const float*)d_in[3];
  const float* Wq   = (const float*)d_in[4];
  float* out = (float*)d_out;

  char* ws = (char*)d_ws;
  unsigned short* WkT = (unsigned short*)(ws);                           // 128 KB
  unsigned short* WqT = (unsigned short*)(ws + (1u << 17));              // 128 KB
  unsigned short* Kf  = (unsigned short*)(ws + (1u << 18));              // 16 MB
  unsigned short* Qf  = (unsigned short*)(ws + (1u << 18) + (1u << 24)); // 16 MB

  prep_wt<<<dim3(256, 2), 256, 0, stream>>>(Wk, WkT, Wq, WqT);

  proj_kernel<<<dim3(256, 2), 256, 0, stream>>>(k_in, WkT, Kf, q_in, WqT, Qf);

  attn_kernel<<<dim3(64, 16), 512, 0, stream>>>(Kf, Qf, adj, out);
}

// Round 10
// 255.845 us; speedup vs baseline: 3.5407x; 1.9453x over previous
//
#include <hip/hip_runtime.h>

#define BATCH 16
#define NQ 2048
#define NK 2048

typedef short s16x8 __attribute__((ext_vector_type(8)));
typedef __bf16 bf16x8 __attribute__((ext_vector_type(8)));
typedef float f32x16 __attribute__((ext_vector_type(16)));
typedef float f32x4 __attribute__((ext_vector_type(4)));
typedef unsigned u32x2 __attribute__((ext_vector_type(2)));

static __device__ __forceinline__ unsigned short f2bf(float f) {
  unsigned u = __builtin_bit_cast(unsigned, f);
  u += 0x7FFFu + ((u >> 16) & 1u);   // round-to-nearest-even
  return (unsigned short)(u >> 16);
}

static __device__ __forceinline__ f32x16 mfma32(s16x8 a, s16x8 b, f32x16 c) {
  return __builtin_amdgcn_mfma_f32_32x32x16_bf16(
      __builtin_bit_cast(bf16x8, a), __builtin_bit_cast(bf16x8, b), c, 0, 0, 0);
}

static __device__ __forceinline__ f32x4 mfma16(s16x8 a, s16x8 b, f32x4 c) {
  return __builtin_amdgcn_mfma_f32_16x16x32_bf16(
      __builtin_bit_cast(bf16x8, a), __builtin_bit_cast(bf16x8, b), c, 0, 0, 0);
}

// p = exp(10*tanh(s) - 10) = exp2(-28.8539.../(e^(2s)+1)), e^(2s)=exp2(2.88539*s)
static __device__ __forceinline__ float score_p(float s) {
  float u = __builtin_amdgcn_exp2f(s * 2.885390081777927f);
  return __builtin_amdgcn_exp2f(-28.853900817779268f * __builtin_amdgcn_rcpf(u + 1.0f));
}

// WT[n][k] = W[k][n] * scale, cast to bf16.  Grid: (256, 2) x 256 thr.
__global__ void prep_wt(const float* __restrict__ Wk, unsigned short* __restrict__ WkT,
                        const float* __restrict__ Wq, unsigned short* __restrict__ WqT) {
  const float* W = blockIdx.y ? Wq : Wk;
  unsigned short* WT = blockIdx.y ? WqT : WkT;
  float scale = blockIdx.y ? 0.0625f : 1.0f;   // fold 1/sqrt(256) into Wq
  int idx = blockIdx.x * 256 + threadIdx.x;
  int n = idx >> 8, k = idx & 255;
  WT[n * 256 + k] = f2bf(W[k * 256 + n] * scale);
}

// Projection; output packed in 16x16x32-MFMA fragment order for 16-row tiles:
//   Yf[((t16*8 + kk)*64 + lane)*8 + j] = Y[row = t16*16 + (lane&15)]
//                                         [e  = kk*32 + (lane>>4)*8 + j]
// so an attn fragment load is 64 lanes x consecutive 16 B = 1 KB coalesced.
__global__ __launch_bounds__(256, 2) void proj_kernel(
    const float* __restrict__ Xk, const unsigned short* __restrict__ WkT,
    unsigned short* __restrict__ Yk,
    const float* __restrict__ Xq, const unsigned short* __restrict__ WqT,
    unsigned short* __restrict__ Yq) {
  const float* X;
  const unsigned short* WT;
  unsigned short* Y;
  if (blockIdx.y == 0) { X = Xk; WT = WkT; Y = Yk; }
  else                 { X = Xq; WT = WqT; Y = Yq; }

  int tid = threadIdx.x;
  int wave = tid >> 6, lane = tid & 63;
  int l31 = lane & 31, kh = lane >> 5;
  int r0 = blockIdx.x * 128 + wave * 32;

  const float* xp = X + (size_t)(r0 + l31) * 256 + kh * 8;

  f32x16 acc[8];
#pragma unroll
  for (int ct = 0; ct < 8; ++ct)
#pragma unroll
    for (int i = 0; i < 16; ++i) acc[ct][i] = 0.0f;

#pragma unroll
  for (int kk = 0; kk < 16; ++kk) {
    f32x4 a0 = *(const f32x4*)(xp + kk * 16);
    f32x4 a1 = *(const f32x4*)(xp + kk * 16 + 4);
    s16x8 af;
#pragma unroll
    for (int j = 0; j < 4; ++j) {
      af[j]     = (short)f2bf(a0[j]);
      af[4 + j] = (short)f2bf(a1[j]);
    }
#pragma unroll
    for (int ct = 0; ct < 8; ++ct) {
      s16x8 bw = *(const s16x8*)(WT + (size_t)(ct * 32 + l31) * 256 + kk * 16 + kh * 8);
      acc[ct] = mfma32(af, bw, acc[ct]);
    }
  }

  // epilogue: scatter into 16-row-tile fragment order
  int kg2 = l31 >> 3, j = l31 & 7;   // e = ct*32 + l31 -> kk=ct, kgroup, elem
#pragma unroll
  for (int ct = 0; ct < 8; ++ct) {
#pragma unroll
    for (int r = 0; r < 16; ++r) {
      int rrow = (r & 3) + 8 * (r >> 2) + 4 * kh;
      int row = r0 + rrow;
      Y[((size_t)((row >> 4) * 8 + ct) * 64 + kg2 * 16 + (row & 15)) * 8 + j] =
          f2bf(acc[ct][r]);
    }
  }
}

// Fused adjacency-pack + scores + tanh-clip + mask + softmax, one-pass.
// Grid: (128, 16) = 2048 blocks of 16 q-rows; 512 threads (8 waves), wave w
// owns cols [w*256, w*256+256) as 16 col-tiles of 16 (mfma 16x16x32).
// Register diet vs the 32-row version: aq 64->32, acc 16->4, rsum 16->4,
// P-stash 64 VGPR -> 64 KB LDS (wave-private slices, b64 write/read-back).
// True VGPR need ~100 <= 128 cap -> no spill; LDS 71 KB -> 2 blocks/CU.
// XCD-aware remap: xcd = lin&7 owns batches {2*xcd, 2*xcd+1} (2 MB K / L2).
__global__ __launch_bounds__(512, 2) void attn_kernel(
    const unsigned short* __restrict__ Kf, const unsigned short* __restrict__ Qf,
    const int* __restrict__ adj, float* __restrict__ out) {
  int lin = blockIdx.y * 128 + blockIdx.x;
  int b  = (lin & 7) * 2 + ((lin >> 3) & 1);
  int qt = lin >> 4;                 // 0..127: 16-row tile within batch
  int q0 = qt * 16;
  int tid = threadIdx.x;
  int wave = tid >> 6, lane = tid & 63;
  int l15 = lane & 15, kg = lane >> 4;
  int colbase = wave * 256;

  __shared__ unsigned plds[8 * 16 * 64 * 2];  // 64 KB: P bf16 [wave][ct][lane][2]
  __shared__ unsigned lmask[8 * 144];         // mask words, row stride 9 (pad)
  __shared__ float wsum[8][16];
  __shared__ float rrecip[16];

  // Q fragments: global tile = b*128 + qt (8 KB, coalesced 1 KB loads)
  const unsigned short* qp = Qf + (size_t)(b * 128 + qt) * 8 * 512;
  s16x8 aq[8];
#pragma unroll
  for (int kk = 0; kk < 8; ++kk)
    aq[kk] = *(const s16x8*)(qp + ((size_t)kk * 64 + lane) * 8);

  // wave-local adjacency pack: 16 rows x 256 cols -> 16x8 mask words
  const int* abase = adj + ((size_t)b * NQ + q0) * (size_t)NK + colbase + lane;
  unsigned* lm = lmask + wave * 144;
#pragma unroll
  for (int r = 0; r < 16; ++r) {
    const int* ap = abase + (size_t)r * NK;
    int a0 = ap[0], a1 = ap[64], a2 = ap[128], a3 = ap[192];
    unsigned long long b0 = __ballot(a0 != 0);
    unsigned long long b1 = __ballot(a1 != 0);
    unsigned long long b2 = __ballot(a2 != 0);
    unsigned long long b3 = __ballot(a3 != 0);
    if (lane < 8) {   // lane j stores word j (cols j*32..j*32+31 of range)
      unsigned long long bb = (lane & 4) ? ((lane & 2) ? b3 : b2)
                                         : ((lane & 2) ? b1 : b0);
      unsigned word = (lane & 1) ? (unsigned)(bb >> 32) : (unsigned)bb;
      lm[r * 9 + lane] = word;
    }
  }
  // no barrier: lmask/plds slices are wave-local (lgkmcnt orders same-wave LDS)

  const unsigned short* kfb = Kf + (size_t)b * 128 * 8 * 512;
  unsigned* pl = plds + (wave * 16) * 128 + lane * 2;

  float rsum[4] = {0.0f, 0.0f, 0.0f, 0.0f};

#pragma unroll 2
  for (int ct = 0; ct < 16; ++ct) {
    f32x4 acc = {0.0f, 0.0f, 0.0f, 0.0f};
    const unsigned short* kpt = kfb + (size_t)(wave * 16 + ct) * 8 * 512;
#pragma unroll
    for (int kk = 0; kk < 8; ++kk) {
      s16x8 bk = *(const s16x8*)(kpt + ((size_t)kk * 64 + lane) * 8);
      acc = mfma16(aq[kk], bk, acc);
    }
    // D[row=kg*4+r][col=l15]; global col = colbase + ct*16 + l15
    unsigned shift = (unsigned)((ct & 1) * 16 + l15);
    float p[4];
#pragma unroll
    for (int r = 0; r < 4; ++r) {
      unsigned mw = lm[(kg * 4 + r) * 9 + (ct >> 1)];
      float e = score_p(acc[r]);
      p[r] = ((mw >> shift) & 1u) ? e : 0.0f;
      rsum[r] += p[r];
    }
    unsigned lo = (unsigned)f2bf(p[0]) | ((unsigned)f2bf(p[1]) << 16);
    unsigned hi = (unsigned)f2bf(p[2]) | ((unsigned)f2bf(p[3]) << 16);
    u32x2 v; v[0] = lo; v[1] = hi;
    *(u32x2*)(pl + ct * 128) = v;
  }

  // col-reduce within each 16-lane quarter (rows disjoint across quarters)
#pragma unroll
  for (int r = 0; r < 4; ++r) {
    float v = rsum[r];
    v += __shfl_xor(v, 1);
    v += __shfl_xor(v, 2);
    v += __shfl_xor(v, 4);
    v += __shfl_xor(v, 8);
    rsum[r] = v;
  }
  if (l15 == 0) {
#pragma unroll
    for (int r = 0; r < 4; ++r) wsum[wave][kg * 4 + r] = rsum[r];
  }
  __syncthreads();
  if (tid < 16) {
    float s = 0.0f;
#pragma unroll
    for (int w = 0; w < 8; ++w) s += wsum[w][tid];
    rrecip[tid] = 1.0f / s;
  }
  __syncthreads();

  float rc[4];
#pragma unroll
  for (int r = 0; r < 4; ++r) rc[r] = rrecip[kg * 4 + r];

  // read P back from LDS, normalize, store
  float* op = out + ((size_t)b * NQ + q0 + kg * 4) * (size_t)NK + colbase + l15;
#pragma unroll 4
  for (int ct = 0; ct < 16; ++ct) {
    u32x2 v = *(const u32x2*)(pl + ct * 128);
    float p0 = __builtin_bit_cast(float, v[0] << 16);
    float p1 = __builtin_bit_cast(float, v[0] & 0xffff0000u);
    float p2 = __builtin_bit_cast(float, v[1] << 16);
    float p3 = __builtin_bit_cast(float, v[1] & 0xffff0000u);
    op[(size_t)0 * NK + ct * 16] = p0 * rc[0];
    op[(size_t)1 * NK + ct * 16] = p1 * rc[1];
    op[(size_t)2 * NK + ct * 16] = p2 * rc[2];
    op[(size_t)3 * NK + ct * 16] = p3 * rc[3];
  }
}

extern "C" void kernel_launch(void* const* d_in, const int* in_sizes, int n_in,
                              void* d_out, int out_size, void* d_ws, size_t ws_size,
                              hipStream_t stream) {
  const float* k_in = (const float*)d_in[0];
  const float* q_in = (const float*)d_in[1];
  const int* adj    = (const int*)d_in[2];
  const float* Wk   = (const float*)d_in[3];
  const float* Wq   = (const float*)d_in[4];
  float* out = (float*)d_out;

  char* ws = (char*)d_ws;
  unsigned short* WkT = (unsigned short*)(ws);                           // 128 KB
  unsigned short* WqT = (unsigned short*)(ws + (1u << 17));              // 128 KB
  unsigned short* Kf  = (unsigned short*)(ws + (1u << 18));              // 16 MB
  unsigned short* Qf  = (unsigned short*)(ws + (1u << 18) + (1u << 24)); // 16 MB

  prep_wt<<<dim3(256, 2), 256, 0, stream>>>(Wk, WkT, Wq, WqT);

  proj_kernel<<<dim3(256, 2), 256, 0, stream>>>(k_in, WkT, Kf, q_in, WqT, Qf);

  attn_kernel<<<dim3(128, 16), 512, 0, stream>>>(Kf, Qf, adj, out);
}